// Round 15
// baseline (153.874 us; speedup 1.0000x reference)
//
#include <hip/hip_runtime.h>
#include <hip/hip_bf16.h>
#include <cstddef>

// MoE gate: B,S,D,E,K = 4,4096,2048,64,2. N = 16384 tokens.
// out layout: dispatch [N][E][K] (2,097,152 f) | combine [N][E][K] | lbl | z
namespace {
constexpr int kD = 2048;
constexpr int kE = 64;
constexpr int kN = 16384;
constexpr size_t kDispatchFloats = (size_t)kN * kE * 2;  // 2,097,152
constexpr size_t kWsplitOff = 1024;  // float offset of W-split region in ws
}

typedef short short8_t __attribute__((ext_vector_type(8)));
typedef float f32x4 __attribute__((ext_vector_type(4)));

// ---------------------------------------------------------------------------
__global__ void zero_ws_kernel(float* __restrict__ ws) {
  ws[threadIdx.x] = 0.0f;  // 256 accumulator slots (129 used)
}

// fp32 -> 3 scaled bf16 splits: x ~= s1 + s2*2^-8 + s3*2^-16 (all normal bf16)
__device__ __forceinline__ void split3(float f, unsigned short& s1,
                                       unsigned short& s2, unsigned short& s3) {
  __hip_bfloat16 h1 = __float2bfloat16(f);
  float r1 = (f - __bfloat162float(h1)) * 256.0f;
  __hip_bfloat16 h2 = __float2bfloat16(r1);
  float r2 = (r1 - __bfloat162float(h2)) * 256.0f;
  __hip_bfloat16 h3 = __float2bfloat16(r2);
  s1 = __builtin_bit_cast(unsigned short, h1);
  s2 = __builtin_bit_cast(unsigned short, h2);
  s3 = __builtin_bit_cast(unsigned short, h3);
}

// 8 floats (2x f32x4) -> one short8 per split (in-register A-fragment convert)
__device__ __forceinline__ void split8(f32x4 a, f32x4 b, short8_t& o1,
                                       short8_t& o2, short8_t& o3) {
  unsigned short s1, s2, s3;
#define SP(v, i, j) \
  split3((v)[i], s1, s2, s3); o1[j]=(short)s1; o2[j]=(short)s2; o3[j]=(short)s3;
  SP(a, 0, 0) SP(a, 1, 1) SP(a, 2, 2) SP(a, 3, 3)
  SP(b, 0, 4) SP(b, 1, 5) SP(b, 2, 6) SP(b, 3, 7)
#undef SP
}

// ---------------------------------------------------------------------------
// Kernel A: pre-split W [64][2048] fp32 -> ws bf16 [3][64][2048] LINEAR
// (768 KB, L2-resident; B-frags are read per-lane, no swizzle needed).
__global__ __launch_bounds__(256)
void split_w_kernel(const float* __restrict__ W, unsigned short* __restrict__ wsp) {
  const int i = blockIdx.x * 256 + threadIdx.x;  // 0..16383
  const float4* src = reinterpret_cast<const float4*>(W) + i * 2;
  const float4 v0 = src[0], v1 = src[1];
  short8_t o1, o2, o3;
  unsigned short s1, s2, s3;
  split3(v0.x, s1, s2, s3); o1[0]=(short)s1; o2[0]=(short)s2; o3[0]=(short)s3;
  split3(v0.y, s1, s2, s3); o1[1]=(short)s1; o2[1]=(short)s2; o3[1]=(short)s3;
  split3(v0.z, s1, s2, s3); o1[2]=(short)s1; o2[2]=(short)s2; o3[2]=(short)s3;
  split3(v0.w, s1, s2, s3); o1[3]=(short)s1; o2[3]=(short)s2; o3[3]=(short)s3;
  split3(v1.x, s1, s2, s3); o1[4]=(short)s1; o2[4]=(short)s2; o3[4]=(short)s3;
  split3(v1.y, s1, s2, s3); o1[5]=(short)s1; o2[5]=(short)s2; o3[5]=(short)s3;
  split3(v1.z, s1, s2, s3); o1[6]=(short)s1; o2[6]=(short)s2; o3[6]=(short)s3;
  split3(v1.w, s1, s2, s3); o1[7]=(short)s1; o2[7]=(short)s2; o3[7]=(short)s3;
  *reinterpret_cast<short8_t*>(wsp + (size_t)0 * 131072 + i * 8) = o1;
  *reinterpret_cast<short8_t*>(wsp + (size_t)1 * 131072 + i * 8) = o2;
  *reinterpret_cast<short8_t*>(wsp + (size_t)2 * 131072 + i * 8) = o3;
}

// ---------------------------------------------------------------------------
// Kernel B: partial logits -- ZERO barriers, ZERO LDS. Grid 2048 =
// 256 tiles x 4 dq x 2 subtiles; block 256 thr = 4 waves = (wr 2 x wc 2);
// wave = 16 tokens x 32 experts, fully independent (no inter-wave coupling).
//   A (x): lane-private contiguous 8-float frags, prefetched one chunk ahead,
//          converted in-register at use (split8).
//   B (W): per-lane 16B reads from the linear pre-split image; 24 KB/chunk
//          working set is L1/L2-hot; 12 loads clustered at chunk start so a
//          single vmcnt-wait amortizes over the chunk's 24 MFMAs.
// Latency hidden by per-wave prefetch + >=4 blocks/CU (VGPR capped at 128).
__global__ __launch_bounds__(256, 4)
void logits_kernel(const float* __restrict__ x,
                   const unsigned short* __restrict__ wsp,
                   float* __restrict__ out) {
  const int tid  = threadIdx.x;
  const int lane = tid & 63;
  const int wv   = __builtin_amdgcn_readfirstlane(tid >> 6);
  const int wr   = wv >> 1;        // 16-token group within subtile
  const int wc   = wv & 1;         // expert half
  const int tile = blockIdx.x & 255;
  const int dq   = (blockIdx.x >> 8) & 3;
  const int sub  = blockIdx.x >> 10;
  const int lrow = lane & 15;
  const int lk   = lane >> 4;      // k-quadrant 0..3

  // A: this lane's token row, k-quarter base
  const float* __restrict__ xrow =
      x + (size_t)(tile * 64 + sub * 32 + wr * 16 + lrow) * kD + dq * 512;
  // B: expert rows for the two nt sub-tiles
  const unsigned short* __restrict__ wb0 =
      wsp + (size_t)(wc * 32 + 0 * 16 + lrow) * kD + dq * 512;
  const unsigned short* __restrict__ wb1 =
      wsp + (size_t)(wc * 32 + 1 * 16 + lrow) * kD + dq * 512;

  f32x4 acc0[2], acc1[2], acc2[2];
  const f32x4 z4 = {0.0f, 0.0f, 0.0f, 0.0f};
#pragma unroll
  for (int nt = 0; nt < 2; ++nt) { acc0[nt] = z4; acc1[nt] = z4; acc2[nt] = z4; }

  // A prefetch regs: [ks*2 + j], statically indexed, chunk-ahead
  f32x4 xc0, xc1, xc2, xc3, xn0, xn1, xn2, xn3;
  {
    const float* p = xrow + lk * 8;
    xc0 = *reinterpret_cast<const f32x4*>(p);
    xc1 = *reinterpret_cast<const f32x4*>(p + 4);
    xc2 = *reinterpret_cast<const f32x4*>(p + 32);
    xc3 = *reinterpret_cast<const f32x4*>(p + 36);
  }

#pragma unroll 2
  for (int c = 0; c < 8; ++c) {
    const int cn = (c + 1) & 7;  // wraps -> uniform count, stays in flight
    // prefetch next A chunk
    {
      const float* p = xrow + cn * 64 + lk * 8;
      xn0 = *reinterpret_cast<const f32x4*>(p);
      xn1 = *reinterpret_cast<const f32x4*>(p + 4);
      xn2 = *reinterpret_cast<const f32x4*>(p + 32);
      xn3 = *reinterpret_cast<const f32x4*>(p + 36);
    }
    // B loads for this chunk, clustered: [ks][nt][split]
    short8_t b[2][2][3];
#pragma unroll
    for (int ks = 0; ks < 2; ++ks) {
      const int ko = c * 64 + ks * 32 + lk * 8;
#pragma unroll
      for (int s = 0; s < 3; ++s) {
        b[ks][0][s] = *reinterpret_cast<const short8_t*>(wb0 + s * 131072 + ko);
        b[ks][1][s] = *reinterpret_cast<const short8_t*>(wb1 + s * 131072 + ko);
      }
    }
    // compute: 2 ksteps x 2 nt x 6 products
#pragma unroll
    for (int ks = 0; ks < 2; ++ks) {
      short8_t a1, a2, a3;
      if (ks == 0) split8(xc0, xc1, a1, a2, a3);
      else         split8(xc2, xc3, a1, a2, a3);
#pragma unroll
      for (int nt = 0; nt < 2; ++nt) {
        acc0[nt] = __builtin_amdgcn_mfma_f32_16x16x32_bf16(a1, b[ks][nt][0], acc0[nt], 0, 0, 0);
        acc1[nt] = __builtin_amdgcn_mfma_f32_16x16x32_bf16(a1, b[ks][nt][1], acc1[nt], 0, 0, 0);
        acc1[nt] = __builtin_amdgcn_mfma_f32_16x16x32_bf16(a2, b[ks][nt][0], acc1[nt], 0, 0, 0);
        acc2[nt] = __builtin_amdgcn_mfma_f32_16x16x32_bf16(a1, b[ks][nt][2], acc2[nt], 0, 0, 0);
        acc2[nt] = __builtin_amdgcn_mfma_f32_16x16x32_bf16(a3, b[ks][nt][0], acc2[nt], 0, 0, 0);
        acc2[nt] = __builtin_amdgcn_mfma_f32_16x16x32_bf16(a2, b[ks][nt][1], acc2[nt], 0, 0, 0);
      }
    }
    xc0 = xn0; xc1 = xn1; xc2 = xn2; xc3 = xn3;  // renamed by unroll-2
  }

  // epilogue: L = acc0 + acc1*2^-8 + acc2*2^-16 -> token's own partial slots
  const float k8 = 1.0f / 256.0f, k16 = 1.0f / 65536.0f;
  float* __restrict__ base = out + ((dq < 2) ? (size_t)0 : kDispatchFloats);
#pragma unroll
  for (int r = 0; r < 4; ++r) {
    const int trow = wr * 16 + lk * 4 + r;            // C row = (lane>>4)*4+r
    const size_t n = (size_t)tile * 64 + sub * 32 + trow;
    float* __restrict__ dst =
        base + n * 128 + (dq & 1) * 64 + wc * 32 + lrow;  // C col = lane&15
#pragma unroll
    for (int nt = 0; nt < 2; ++nt)
      dst[nt * 16] = acc0[nt][r] + acc1[nt][r] * k8 + acc2[nt][r] * k16;
  }
}

// ---------------------------------------------------------------------------
// Kernel C: sum 4 partials -> logits, softmax, top-2, outputs, losses.
__global__ __launch_bounds__(256)
void gate_kernel(float* __restrict__ out, float* __restrict__ ws) {
  __shared__ float lg[64][65];
  __shared__ int ti0[64], ti1[64];
  __shared__ float tv0[64], tv1[64], tz2[64];
  const int tid  = threadIdx.x;
  const int tile = blockIdx.x;

  float* __restrict__ outd = out + (size_t)tile * 8192;
  float* __restrict__ outc = out + kDispatchFloats + (size_t)tile * 8192;
  const float4* __restrict__ d4 = reinterpret_cast<const float4*>(outd);
  const float4* __restrict__ c4 = reinterpret_cast<const float4*>(outc);

  const int tq = tid >> 4, q = tid & 15;
#pragma unroll
  for (int k = 0; k < 4; ++k) {
    const int t = k * 16 + tq;
    const float4 a = d4[t * 32 + q];
    const float4 b = d4[t * 32 + 16 + q];
    const float4 c = c4[t * 32 + q];
    const float4 d = c4[t * 32 + 16 + q];
    lg[t][q * 4 + 0] = a.x + b.x + c.x + d.x;
    lg[t][q * 4 + 1] = a.y + b.y + c.y + d.y;
    lg[t][q * 4 + 2] = a.z + b.z + c.z + d.z;
    lg[t][q * 4 + 3] = a.w + b.w + c.w + d.w;
  }
  __syncthreads();

  if (tid < 64) {
    float v0 = -INFINITY, v1 = -INFINITY;
    int i0 = 0, i1 = 0;
    for (int e = 0; e < kE; ++e) {
      const float l = lg[tid][e];
      if (l > v0) { v1 = v0; i1 = i0; v0 = l; i0 = e; }
      else if (l > v1) { v1 = l; i1 = e; }
    }
    const float m = v0;
    float s = 0.0f;
    for (int e = 0; e < kE; ++e) s += __expf(lg[tid][e] - m);
    const float rs = 1.0f / s;
    float zexp = 0.0f;
    for (int e = 0; e < kE; ++e) zexp += __expf(__expf(lg[tid][e] - m) * rs);
    const float z = logf(zexp);
    ti0[tid] = i0; ti1[tid] = i1;
    tv0[tid] = rs;                    // exp(v0-m)*rs with v0==m
    tv1[tid] = __expf(v1 - m) * rs;
    tz2[tid] = z * z;
  }
  __syncthreads();

  if (tid < kE) {
    float g = 0.0f, cnt = 0.0f;
    for (int t = 0; t < 64; ++t) {
      if (ti0[t] == tid) { g += tv0[t]; cnt += 1.0f; }
      if (ti1[t] == tid) { g += tv1[t]; cnt += 1.0f; }
    }
    atomicAdd(&ws[tid], g);
    atomicAdd(&ws[kE + tid], cnt);
    float z2 = tz2[tid];
    for (int off = 32; off; off >>= 1) z2 += __shfl_down(z2, off);
    if (tid == 0) atomicAdd(&ws[2 * kE], z2);
  }

  {
    const int t = tid >> 2, sub = tid & 3;
    const int i0 = ti0[t], i1 = ti1[t];
    const float v0 = tv0[t], v1 = tv1[t];
    float4* __restrict__ dp = reinterpret_cast<float4*>(outd) + t * 32;
    float4* __restrict__ cp = reinterpret_cast<float4*>(outc) + t * 32;
#pragma unroll
    for (int j = 0; j < 8; ++j) {
      const int qq = sub * 8 + j;
      const int e0 = qq * 2, e1 = qq * 2 + 1;
      const float d0v = (e0 == i0 || e0 == i1) ? 1.0f : 0.0f;
      const float d1v = (e1 == i0 || e1 == i1) ? 1.0f : 0.0f;
      const float c0 = (e0 == i0) ? v0 : ((e0 == i1) ? v1 : 0.0f);
      const float c1 = (e1 == i0) ? v0 : ((e1 == i1) ? v1 : 0.0f);
      dp[qq] = make_float4(d0v, 0.0f, d1v, 0.0f);
      cp[qq] = make_float4(c0, 0.0f, c1, 0.0f);
    }
  }
}

// ---------------------------------------------------------------------------
__global__ void finalize_kernel(const float* __restrict__ ws,
                                float* __restrict__ out) {
  const int e = threadIdx.x;  // 64 threads
  float prod = ws[e] * ws[kE + e];
  for (int off = 32; off; off >>= 1) prod += __shfl_down(prod, off);
  if (e == 0) {
    const size_t base = kDispatchFloats * 2;
    const float invN = 1.0f / (float)kN;
    out[base]     = prod * ((float)kE * invN * invN);  // load_balancing_loss
    out[base + 1] = ws[2 * kE] * invN;                 // router_z_loss
  }
}

// ---------------------------------------------------------------------------
extern "C" void kernel_launch(void* const* d_in, const int* in_sizes, int n_in,
                              void* d_out, int out_size, void* d_ws,
                              size_t ws_size, hipStream_t stream) {
  const float* x = (const float*)d_in[0];  // [4,4096,2048] fp32
  const float* W = (const float*)d_in[1];  // [64,2048] fp32
  float* out = (float*)d_out;
  float* ws = (float*)d_ws;
  unsigned short* wsp = (unsigned short*)(ws + kWsplitOff);

  zero_ws_kernel<<<1, 256, 0, stream>>>(ws);
  split_w_kernel<<<64, 256, 0, stream>>>(W, wsp);
  logits_kernel<<<2048, 256, 0, stream>>>(x, wsp, out);
  gate_kernel<<<256, 256, 0, stream>>>(out, ws);
  finalize_kernel<<<1, kE, 0, stream>>>(ws, out);
}